// Round 6
// baseline (19.432 us; speedup 1.0000x reference)
//
#include <hip/hip_runtime.h>
#include <math.h>

#define NV      6890
#define BLOCK   1024
#define NWAVES  (BLOCK / 64)
#define DENSITY 985.0f
#define EPS     1e-12f

typedef float v2f __attribute__((ext_vector_type(2)));

__device__ __forceinline__ float frcp(float x)  { return __builtin_amdgcn_rcpf(x); }
__device__ __forceinline__ float fsqrt(float x) { return __builtin_amdgcn_sqrtf(x); }

__global__ __launch_bounds__(BLOCK) void measure_kernel(
    const float* __restrict__ v,        // (B, NV, 3)
    const int*   __restrict__ faces,    // (F, 3)
    const int*   __restrict__ circ_idx, // (3,)
    const int*   __restrict__ h_idx,    // (2,)
    float*       __restrict__ out,      // (B, 5)
    int F)
{
    // LDS layout: xz (float2[NV]) | y (float[NV]) | red (NWAVES*4)
    extern __shared__ float lds[];
    v2f*   xzs = reinterpret_cast<v2f*>(lds);
    float* ys  = lds + 2 * NV;
    float* red = ys + NV;

    const int b = blockIdx.x;
    const float* vb = v + (size_t)b * NV * 3;

    // stage this batch's vertices into split LDS arrays
    for (int i = threadIdx.x; i < NV; i += BLOCK) {
        const float* p = vb + 3 * i;
        const float x = p[0], y = p[1], z = p[2];
        ys[i] = y;
        xzs[i] = (v2f){ x, z };
    }
    __syncthreads();

    const float pys[3] = { ys[circ_idx[0]], ys[circ_idx[1]], ys[circ_idx[2]] };

    float vol = 0.0f;
    float circ[3] = {0.0f, 0.0f, 0.0f};

    // unroll 4: 4 independent load->gather->compute chains per wave in flight
    // (16 chains/SIMD at 4 waves/SIMD) to cover L2 + LDS latency.
    #pragma unroll 4
    for (int f = threadIdx.x; f < F; f += BLOCK) {
        const int i0 = faces[3 * f + 0];
        const int i1 = faces[3 * f + 1];
        const int i2 = faces[3 * f + 2];

        const float y0 = ys[i0], y1 = ys[i1], y2 = ys[i2];
        const v2f xz0 = xzs[i0];   // {x, z}
        const v2f xz1 = xzs[i1];
        const v2f xz2 = xzs[i2];

        // signed volume term: v0 . (v1 x v2)
        {
            const float cx = y1 * xz2.y - xz1.y * y2;
            const float cy = xz1.y * xz2.x - xz1.x * xz2.y;
            const float cz = xz1.x * y2 - y1 * xz2.x;
            vol += xz0.x * cx + y0 * cy + xz0.y * cz;
        }

        // plane-invariant edge data
        const float r01 = frcp(y0 - y1);
        const float r12 = frcp(y1 - y2);
        const float r20 = frcp(y2 - y0);
        const v2f e01 = xz1 - xz0;
        const v2f e12 = xz2 - xz1;
        const v2f e20 = xz0 - xz2;

        #pragma unroll
        for (int p = 0; p < 3; ++p) {
            const float py = pys[p];
            const float d0 = y0 - py;
            const float d1 = y1 - py;
            const float d2 = y2 - py;
            const bool c0 = (d0 * d1) < 0.0f;   // edge v0->v1 crosses
            const bool c1 = (d1 * d2) < 0.0f;   // edge v1->v2
            const bool c2 = (d2 * d0) < 0.0f;   // edge v2->v0

            const float t0 = d0 * r01;          // garbage unless selected
            const float t1 = d1 * r12;
            const float t2 = d2 * r20;

            const v2f q0 = t0 * e01 + xz0;      // v_pk_fma_f32
            const v2f q1 = t1 * e12 + xz1;
            const v2f q2 = t2 * e20 + xz2;

            // crossings come in pairs (0 or exactly 2); endpoints {q_i : c_i}
            const v2f qA = c0 ? q0 : q1;
            const v2f qB = c2 ? q2 : q1;
            const bool any = c0 || c1 || c2;

            const v2f  d  = qA - qB;
            const float L = fsqrt(fmaf(d.x, d.x, fmaf(d.y, d.y, EPS)));
            circ[p] += any ? L : 0.0f;
        }
    }

    // wave-level reduction (wave = 64)
    #pragma unroll
    for (int off = 32; off > 0; off >>= 1) {
        vol     += __shfl_down(vol,     off);
        circ[0] += __shfl_down(circ[0], off);
        circ[1] += __shfl_down(circ[1], off);
        circ[2] += __shfl_down(circ[2], off);
    }
    const int lane = threadIdx.x & 63;
    const int wid  = threadIdx.x >> 6;
    if (lane == 0) {
        red[wid * 4 + 0] = vol;
        red[wid * 4 + 1] = circ[0];
        red[wid * 4 + 2] = circ[1];
        red[wid * 4 + 3] = circ[2];
    }
    __syncthreads();

    if (threadIdx.x == 0) {
        float tv = 0.f, t0 = 0.f, t1 = 0.f, t2 = 0.f;
        for (int w = 0; w < NWAVES; ++w) {
            tv += red[w * 4 + 0];
            t0 += red[w * 4 + 1];
            t1 += red[w * 4 + 2];
            t2 += red[w * 4 + 3];
        }
        const float mass = fabsf(tv / 6.0f) * DENSITY;
        const float hy0 = ys[h_idx[0]];
        const float hy1 = ys[h_idx[1]];
        out[b * 5 + 0] = mass;
        out[b * 5 + 1] = fabsf(hy0 - hy1);
        out[b * 5 + 2] = t0;
        out[b * 5 + 3] = t1;
        out[b * 5 + 4] = t2;
    }
}

extern "C" void kernel_launch(void* const* d_in, const int* in_sizes, int n_in,
                              void* d_out, int out_size, void* d_ws, size_t ws_size,
                              hipStream_t stream) {
    const float* v        = (const float*)d_in[0];
    const int*   faces    = (const int*)d_in[1];
    const int*   circ_idx = (const int*)d_in[2];
    const int*   h_idx    = (const int*)d_in[3];
    float*       out      = (float*)d_out;

    const int B = in_sizes[0] / (NV * 3);   // 256
    const int F = in_sizes[1] / 3;          // 13776

    const size_t lds_bytes = (size_t)(3 * NV + NWAVES * 4) * sizeof(float);
    measure_kernel<<<B, BLOCK, lds_bytes, stream>>>(v, faces, circ_idx, h_idx, out, F);
}

// Round 7
// 18.444 us; speedup vs baseline: 1.0535x; 1.0535x over previous
//
#include <hip/hip_runtime.h>
#include <math.h>

#define NV      6890
#define BLOCK   1024
#define NWAVES  (BLOCK / 64)
#define DENSITY 985.0f

typedef float v2f __attribute__((ext_vector_type(2)));

__device__ __forceinline__ float frcp(float x)  { return __builtin_amdgcn_rcpf(x); }
__device__ __forceinline__ float fsqrt(float x) { return __builtin_amdgcn_sqrtf(x); }

__global__ __launch_bounds__(BLOCK) void measure_kernel(
    const float* __restrict__ v,        // (B, NV, 3)
    const int*   __restrict__ faces,    // (F, 3)
    const int*   __restrict__ circ_idx, // (3,)
    const int*   __restrict__ h_idx,    // (2,)
    float*       __restrict__ out,      // (B, 5)
    int F)
{
    // LDS layout: xz (float2[NV]) | y (float[NV]) | red (NWAVES*4)
    extern __shared__ float lds[];
    v2f*   xzs = reinterpret_cast<v2f*>(lds);
    float* ys  = lds + 2 * NV;
    float* red = ys + NV;

    const int b = blockIdx.x;
    const float* vb = v + (size_t)b * NV * 3;

    // ---- staging: float2 global loads, merged LDS writes (NV is even) ----
    {
        const v2f* vb2 = reinterpret_cast<const v2f*>(vb);   // 8B-aligned for all b
        const int NSLOT = NV / 2;                            // 2 verts per slot
        for (int j = threadIdx.x; j < NSLOT; j += BLOCK) {
            const v2f a = vb2[3 * j + 0];   // (x0, y0)
            const v2f m = vb2[3 * j + 1];   // (z0, x1)
            const v2f c = vb2[3 * j + 2];   // (y1, z1)
            ys[2 * j + 0] = a.y;
            ys[2 * j + 1] = c.x;
            xzs[2 * j + 0] = (v2f){ a.x, m.x };
            xzs[2 * j + 1] = (v2f){ m.y, c.y };
        }
    }
    __syncthreads();

    const float pys[3] = { ys[circ_idx[0]], ys[circ_idx[1]], ys[circ_idx[2]] };

    float vol = 0.0f;
    float circ[3] = {0.0f, 0.0f, 0.0f};

    #pragma unroll 2
    for (int f = threadIdx.x; f < F; f += BLOCK) {
        const int i0 = faces[3 * f + 0];
        const int i1 = faces[3 * f + 1];
        const int i2 = faces[3 * f + 2];

        const float y0 = ys[i0], y1 = ys[i1], y2 = ys[i2];
        const v2f xz0 = xzs[i0];   // {x, z}
        const v2f xz1 = xzs[i1];
        const v2f xz2 = xzs[i2];

        // signed volume term: v0 . (v1 x v2)
        {
            const float cx = y1 * xz2.y - xz1.y * y2;
            const float cy = xz1.y * xz2.x - xz1.x * xz2.y;
            const float cz = xz1.x * y2 - y1 * xz2.x;
            vol += xz0.x * cx + y0 * cy + xz0.y * cz;
        }

        // ---- plane-invariant per-edge slopes and candidate segment factors ----
        // g_PQ = (xz_Q - xz_P) / (y_P - y_Q)  (symmetric under P<->Q swap).
        // Segment for odd vertex P with partners Q,R:  L = |d_P| * |g_PQ - g_PR|.
        const v2f g01 = (xz1 - xz0) * frcp(y0 - y1);
        const v2f g12 = (xz2 - xz1) * frcp(y1 - y2);
        const v2f g20 = (xz0 - xz2) * frcp(y2 - y0);

        const v2f w0 = g01 - g20;   // odd = v0 (edges 01 & 20 cross)
        const v2f w1 = g01 - g12;   // odd = v1 (edges 01 & 12 cross)
        const v2f w2 = g12 - g20;   // odd = v2 (edges 12 & 20 cross)
        const float h0 = fsqrt(fmaf(w0.x, w0.x, w0.y * w0.y));
        const float h1 = fsqrt(fmaf(w1.x, w1.x, w1.y * w1.y));
        const float h2 = fsqrt(fmaf(w2.x, w2.x, w2.y * w2.y));

        #pragma unroll
        for (int p = 0; p < 3; ++p) {
            const float py = pys[p];
            const float d0 = y0 - py;
            const float d1 = y1 - py;
            const float d2 = y2 - py;
            const bool c0 = (d0 * d1) < 0.0f;   // edge v0->v1 crosses
            const bool c1 = (d1 * d2) < 0.0f;   // edge v1->v2
            const bool c2 = (d2 * d0) < 0.0f;   // edge v2->v0

            // odd vertex: 0 iff c0&c2, 1 iff c0&c1, 2 iff c1&c2
            float dsel = c2 ? d0 : d1;
            float hsel = c2 ? h0 : h1;
            dsel = c0 ? dsel : d2;
            hsel = c0 ? hsel : h2;
            const bool valid = (c0 && c1) || (c1 && c2) || (c2 && c0);

            const float L = fabsf(dsel) * hsel;  // abs is a free src modifier
            circ[p] += valid ? L : 0.0f;
        }
    }

    // wave-level reduction (wave = 64)
    #pragma unroll
    for (int off = 32; off > 0; off >>= 1) {
        vol     += __shfl_down(vol,     off);
        circ[0] += __shfl_down(circ[0], off);
        circ[1] += __shfl_down(circ[1], off);
        circ[2] += __shfl_down(circ[2], off);
    }
    const int lane = threadIdx.x & 63;
    const int wid  = threadIdx.x >> 6;
    if (lane == 0) {
        red[wid * 4 + 0] = vol;
        red[wid * 4 + 1] = circ[0];
        red[wid * 4 + 2] = circ[1];
        red[wid * 4 + 3] = circ[2];
    }
    __syncthreads();

    if (threadIdx.x == 0) {
        float tv = 0.f, t0 = 0.f, t1 = 0.f, t2 = 0.f;
        for (int w = 0; w < NWAVES; ++w) {
            tv += red[w * 4 + 0];
            t0 += red[w * 4 + 1];
            t1 += red[w * 4 + 2];
            t2 += red[w * 4 + 3];
        }
        const float mass = fabsf(tv / 6.0f) * DENSITY;
        const float hy0 = ys[h_idx[0]];
        const float hy1 = ys[h_idx[1]];
        out[b * 5 + 0] = mass;
        out[b * 5 + 1] = fabsf(hy0 - hy1);
        out[b * 5 + 2] = t0;
        out[b * 5 + 3] = t1;
        out[b * 5 + 4] = t2;
    }
}

extern "C" void kernel_launch(void* const* d_in, const int* in_sizes, int n_in,
                              void* d_out, int out_size, void* d_ws, size_t ws_size,
                              hipStream_t stream) {
    const float* v        = (const float*)d_in[0];
    const int*   faces    = (const int*)d_in[1];
    const int*   circ_idx = (const int*)d_in[2];
    const int*   h_idx    = (const int*)d_in[3];
    float*       out      = (float*)d_out;

    const int B = in_sizes[0] / (NV * 3);   // 256
    const int F = in_sizes[1] / 3;          // 13776

    const size_t lds_bytes = (size_t)(3 * NV + NWAVES * 4) * sizeof(float);
    measure_kernel<<<B, BLOCK, lds_bytes, stream>>>(v, faces, circ_idx, h_idx, out, F);
}